// Round 1
// baseline (123.543 us; speedup 1.0000x reference)
//
#include <hip/hip_runtime.h>

constexpr int B_ = 16;
constexpr int N_ = 500;
constexpr int NC = 10;
constexpr int FM_ = 360;
constexpr int RMAXC = 12;
constexpr long HM_ELEMS = (long)B_ * NC * FM_ * FM_;      // 20,736,000
constexpr long ANNO_OFF = HM_ELEMS;                        // +16*500*8 = 64,000
constexpr long IND_OFF  = ANNO_OFF + (long)B_ * N_ * 8;    // 20,800,000
constexpr long MASK_OFF = IND_OFF + (long)B_ * N_;         // 20,808,000

__global__ void zero_hm_kernel(float4* __restrict__ hm, int n4) {
    int i = blockIdx.x * blockDim.x + threadIdx.x;
    int stride = gridDim.x * blockDim.x;
    float4 z = {0.f, 0.f, 0.f, 0.f};
    for (int k = i; k < n4; k += stride) hm[k] = z;
}

// Stable counting sort by label (ascending, ties by original index) ==
// jnp.argsort(labels, axis=1, stable=True). One thread per batch row.
__global__ void sort_kernel(const int* __restrict__ labels, int* __restrict__ order) {
    int b = threadIdx.x;
    if (b >= B_) return;
    const int* lab = labels + b * N_;
    int* ord = order + b * N_;
    int cnt[NC + 1];
    for (int c = 0; c <= NC; ++c) cnt[c] = 0;
    for (int i = 0; i < N_; ++i) cnt[lab[i]]++;        // labels are 1..10
    int base[NC + 1];
    int s = 0;
    for (int c = 1; c <= NC; ++c) { base[c] = s; s += cnt[c]; }
    for (int i = 0; i < N_; ++i) ord[base[lab[i]]++] = i;
}

__global__ __launch_bounds__(64) void obj_kernel(
        const float* __restrict__ boxes, const int* __restrict__ labels,
        const int* __restrict__ order, float* __restrict__ out) {
    int obj = blockIdx.x;               // 0 .. B*N-1, = b*N + sorted position p
    int b = obj / N_;
    int p = obj - b * N_;
    int orig = order[b * N_ + p];
    const float* bx = boxes + (long)(b * N_ + orig) * 9;
    float x = bx[0], y = bx[1], zz = bx[2];
    float w = bx[3], l = bx[4], h = bx[5];
    float rot = bx[8];
    int cls = labels[b * N_ + orig] - 1;

    // Replicate reference float32 op order exactly.
    float wp = w / 0.075f / 4.0f;
    float lp = l / 0.075f / 4.0f;
    float cx_f = (x + 54.0f) / 0.075f / 4.0f;   // (x - PCR0), PCR0 = -54.0
    float cy_f = (y + 54.0f) / 0.075f / 4.0f;
    int cx = (int)cx_f;                          // trunc == .astype(int32)
    int cy = (int)cy_f;
    bool valid = (wp > 0.0f) && (lp > 0.0f) &&
                 (cx >= 0) && (cx < FM_) && (cy >= 0) && (cy < FM_);

    // gaussian_radius(height=lp, width=wp, min_overlap=0.1)
    float height = lp, width = wp;
    float b1 = height + width;
    float c1 = width * height * 0.9f / 1.1f;
    float r1 = (b1 + sqrtf(b1 * b1 - 4.0f * c1)) / 2.0f;
    float b2 = 2.0f * (height + width);
    float c2 = 0.9f * width * height;
    float r2 = (b2 + sqrtf(b2 * b2 - 16.0f * c2)) / 2.0f;
    float b3 = -0.2f * (height + width);
    float c3 = -0.9f * width * height;
    float r3 = (b3 + sqrtf(b3 * b3 - 1.6f * c3)) / 2.0f;
    float r = fminf(fminf(r1, r2), r3);
    int radius = max(2, (int)floorf(r));
    float sigma = (2.0f * (float)radius + 1.0f) / 6.0f;

    if (threadIdx.x == 0) {
        float* anno = out + ANNO_OFF + (long)(b * N_ + p) * 8;
        if (valid) {
            anno[0] = cx_f - (float)cx;
            anno[1] = cy_f - (float)cy;
            anno[2] = zz;
            anno[3] = logf(w);
            anno[4] = logf(l);
            anno[5] = logf(h);
            anno[6] = sinf(rot);
            anno[7] = cosf(rot);
            out[IND_OFF + b * N_ + p]  = (float)(cy * FM_ + cx);
            out[MASK_OFF + b * N_ + p] = 1.0f;
        } else {
            #pragma unroll
            for (int i = 0; i < 8; ++i) anno[i] = 0.0f;
            out[IND_OFF + b * N_ + p]  = 0.0f;
            out[MASK_OFF + b * N_ + p] = 0.0f;
        }
    }

    if (!valid) return;

    // Gaussian window scatter-max; reference window is |dx|,|dy| <= min(radius, R_MAX)
    int reff = min(radius, RMAXC);
    int wsz = 2 * reff + 1;
    int total = wsz * wsz;
    float denom = 2.0f * (sigma * sigma);       // 2 * sigma**2, exact op order
    float* hm = out + ((long)b * NC + cls) * FM_ * FM_;
    for (int c = threadIdx.x; c < total; c += 64) {
        int dy = c / wsz - reff;
        int dx = c - (c / wsz) * wsz - reff;
        int yy = cy + dy, xx = cx + dx;
        if (yy < 0 || yy >= FM_ || xx < 0 || xx >= FM_) continue;
        float d2 = (float)(dx * dx + dy * dy);
        float g = expf(-d2 / denom);
        // g >= 0 and heatmap init 0: int-view atomicMax preserves float order.
        atomicMax((int*)&hm[yy * FM_ + xx], __float_as_int(g));
    }
}

extern "C" void kernel_launch(void* const* d_in, const int* in_sizes, int n_in,
                              void* d_out, int out_size, void* d_ws, size_t ws_size,
                              hipStream_t stream) {
    const float* boxes = (const float*)d_in[0];
    const int* labels  = (const int*)d_in[1];
    float* out = (float*)d_out;
    int* order = (int*)d_ws;                    // 16*500*4 = 32 KB scratch

    sort_kernel<<<1, 64, 0, stream>>>(labels, order);
    zero_hm_kernel<<<2048, 256, 0, stream>>>((float4*)out, (int)(HM_ELEMS / 4));
    obj_kernel<<<B_ * N_, 64, 0, stream>>>(boxes, labels, order, out);
}

// Round 2
// 46.174 us; speedup vs baseline: 2.6756x; 2.6756x over previous
//
#include <hip/hip_runtime.h>

constexpr int B_ = 16;
constexpr int N_ = 500;
constexpr int NC = 10;
constexpr int FM_ = 360;
constexpr int RMAXC = 12;
constexpr long HM_ELEMS = (long)B_ * NC * FM_ * FM_;      // 20,736,000
constexpr long ANNO_OFF = HM_ELEMS;                        // +16*500*8 = 64,000
constexpr long IND_OFF  = ANNO_OFF + (long)B_ * N_ * 8;    // 20,800,000
constexpr long MASK_OFF = IND_OFF + (long)B_ * N_;         // 20,808,000

__global__ void zero_hm_kernel(float4* __restrict__ hm, int n4) {
    int i = blockIdx.x * blockDim.x + threadIdx.x;
    int stride = gridDim.x * blockDim.x;
    float4 z = {0.f, 0.f, 0.f, 0.f};
    for (int k = i; k < n4; k += stride) hm[k] = z;
}

// pos[i] = stable-sort-by-label position of original element i:
//   #(j: lab[j] < lab[i]) + #(j < i: lab[j] == lab[i])
// One block per batch; labels staged in LDS; 500-iter broadcast loop per thread.
__global__ __launch_bounds__(512) void rank_kernel(const int* __restrict__ labels,
                                                   int* __restrict__ pos) {
    int b = blockIdx.x;
    __shared__ int lab[N_];
    for (int i = threadIdx.x; i < N_; i += 512) lab[i] = labels[b * N_ + i];
    __syncthreads();
    int i = threadIdx.x;
    if (i < N_) {
        int c = lab[i];
        int rank = 0;
        #pragma unroll 4
        for (int j = 0; j < N_; ++j) {
            int lj = lab[j];
            rank += (lj < c) | ((lj == c) & (j < i));
        }
        pos[b * N_ + i] = rank;
    }
}

__global__ __launch_bounds__(64) void obj_kernel(
        const float* __restrict__ boxes, const int* __restrict__ labels,
        const int* __restrict__ pos, float* __restrict__ out) {
    int obj = blockIdx.x;               // 0 .. B*N-1 = b*N + ORIGINAL index i
    int b = obj / N_;
    int i = obj - b * N_;
    int p = pos[obj];                   // sorted output slot
    const float* bx = boxes + (long)obj * 9;
    float x = bx[0], y = bx[1], zz = bx[2];
    float w = bx[3], l = bx[4], h = bx[5];
    float rot = bx[8];
    int cls = labels[obj] - 1;

    // Replicate reference float32 op order exactly.
    float wp = w / 0.075f / 4.0f;
    float lp = l / 0.075f / 4.0f;
    float cx_f = (x + 54.0f) / 0.075f / 4.0f;   // (x - PCR0), PCR0 = -54.0
    float cy_f = (y + 54.0f) / 0.075f / 4.0f;
    int cx = (int)cx_f;                          // trunc == .astype(int32)
    int cy = (int)cy_f;
    bool valid = (wp > 0.0f) && (lp > 0.0f) &&
                 (cx >= 0) && (cx < FM_) && (cy >= 0) && (cy < FM_);

    // gaussian_radius(height=lp, width=wp, min_overlap=0.1)
    float height = lp, width = wp;
    float b1 = height + width;
    float c1 = width * height * 0.9f / 1.1f;
    float r1 = (b1 + sqrtf(b1 * b1 - 4.0f * c1)) / 2.0f;
    float b2 = 2.0f * (height + width);
    float c2 = 0.9f * width * height;
    float r2 = (b2 + sqrtf(b2 * b2 - 16.0f * c2)) / 2.0f;
    float b3 = -0.2f * (height + width);
    float c3 = -0.9f * width * height;
    float r3 = (b3 + sqrtf(b3 * b3 - 1.6f * c3)) / 2.0f;
    float r = fminf(fminf(r1, r2), r3);
    int radius = max(2, (int)floorf(r));
    float sigma = (2.0f * (float)radius + 1.0f) / 6.0f;

    if (threadIdx.x == 0) {
        float* anno = out + ANNO_OFF + (long)(b * N_ + p) * 8;
        if (valid) {
            anno[0] = cx_f - (float)cx;
            anno[1] = cy_f - (float)cy;
            anno[2] = zz;
            anno[3] = logf(w);
            anno[4] = logf(l);
            anno[5] = logf(h);
            anno[6] = sinf(rot);
            anno[7] = cosf(rot);
            out[IND_OFF + b * N_ + p]  = (float)(cy * FM_ + cx);
            out[MASK_OFF + b * N_ + p] = 1.0f;
        } else {
            #pragma unroll
            for (int k = 0; k < 8; ++k) anno[k] = 0.0f;
            out[IND_OFF + b * N_ + p]  = 0.0f;
            out[MASK_OFF + b * N_ + p] = 0.0f;
        }
    }

    if (!valid) return;

    // Gaussian window scatter-max; window is |dx|,|dy| <= min(radius, R_MAX)
    int reff = min(radius, RMAXC);
    int wsz = 2 * reff + 1;
    int total = wsz * wsz;
    float denom = 2.0f * (sigma * sigma);       // 2 * sigma**2, exact op order
    float* hm = out + ((long)b * NC + cls) * FM_ * FM_;
    for (int c = threadIdx.x; c < total; c += 64) {
        int q = c / wsz;
        int dy = q - reff;
        int dx = c - q * wsz - reff;
        int yy = cy + dy, xx = cx + dx;
        if (yy < 0 || yy >= FM_ || xx < 0 || xx >= FM_) continue;
        float d2 = (float)(dx * dx + dy * dy);
        float g = expf(-d2 / denom);
        // g >= 0 and heatmap init 0: int-view atomicMax preserves float order.
        atomicMax((int*)&hm[yy * FM_ + xx], __float_as_int(g));
    }
}

extern "C" void kernel_launch(void* const* d_in, const int* in_sizes, int n_in,
                              void* d_out, int out_size, void* d_ws, size_t ws_size,
                              hipStream_t stream) {
    const float* boxes = (const float*)d_in[0];
    const int* labels  = (const int*)d_in[1];
    float* out = (float*)d_out;
    int* pos = (int*)d_ws;                      // 16*500*4 = 32 KB scratch

    rank_kernel<<<B_, 512, 0, stream>>>(labels, pos);
    zero_hm_kernel<<<2048, 256, 0, stream>>>((float4*)out, (int)(HM_ELEMS / 4));
    obj_kernel<<<B_ * N_, 64, 0, stream>>>(boxes, labels, pos, out);
}